// Round 1
// baseline (607.992 us; speedup 1.0000x reference)
//
#include <hip/hip_runtime.h>
#include <stdint.h>

#pragma clang fp contract(off)

#define N_PRIORS   400000
#define NCLS       81
#define TILE       128
#define RED_BLOCKS (N_PRIORS / TILE)   // 3125
#define HGRID      512
#define CAND_CAP   8192
#define TOPK       1000

// ---- workspace layout (bytes). First 65536 bytes zeroed each launch. ----
#define OFF_CTRL   0        // u32 ctrl[16]: [0]=prefix [1]=krem [2]=cand_cnt [3..6]=done counters
#define OFF_HIST0  64       // u32[256]
#define OFF_HIST1  1088
#define OFF_HIST2  2112
#define OFF_RNZ    3200     // u64[16] row-nonzero bits
#define OFF_VALID  3328     // u64[16] valid bits (score > 0.3)
#define OFF_CSCORE 4096     // f32[1024]
#define OFF_CLABEL 8192     // s32[1024]
#define OFF_CRAW   12288    // f32[1024][4] raw boxes
#define OFF_OBOX   28672    // f32[1024][4] offset boxes
#define OFF_OAREA  45056    // f32[1024]
#define OFF_CAND   65536    // u64[8192]
#define OFF_M      131072   // u64[1000][16] suppression bit-matrix
#define OFF_KEYS   262144   // u64[400000]
#define OFF_LABELS (OFF_KEYS + N_PRIORS * 8)  // s32[400000]

__device__ __forceinline__ uint32_t atomLoadU32(const uint32_t* p) {
  return __hip_atomic_load(p, __ATOMIC_RELAXED, __HIP_MEMORY_SCOPE_AGENT);
}
__device__ __forceinline__ uint64_t atomLoadU64(const uint64_t* p) {
  return __hip_atomic_load(p, __ATOMIC_RELAXED, __HIP_MEMORY_SCOPE_AGENT);
}
__device__ __forceinline__ void atomStoreU64(uint64_t* p, uint64_t v) {
  __hip_atomic_store(p, v, __ATOMIC_RELAXED, __HIP_MEMORY_SCOPE_AGENT);
}

// single-thread digit selection: find digit d (desc) with cum(>d) < k <= cum(>=d)
__device__ void select_digit(const uint32_t* hist, uint32_t k, uint32_t prefix,
                             int sh_dig, uint32_t* ctrl) {
  uint32_t cum = 0;
  for (int b = 255; b >= 0; --b) {
    uint32_t h = atomLoadU32(&hist[b]);
    if (cum + h >= k) {
      ctrl[0] = prefix | ((uint32_t)b << sh_dig);
      ctrl[1] = k - cum;
      return;
    }
    cum += h;
  }
  ctrl[0] = prefix;  // unreachable for valid input
  ctrl[1] = 0;
}

// ---- Phase 1: per-prior max/argmax over classes 1..80 + key pack + hist pass 0 ----
__global__ __launch_bounds__(256) void k_reduce(const float* __restrict__ scores,
                                                uint8_t* __restrict__ ws) {
  __shared__ float s_tile[TILE * NCLS];     // 41472 B
  __shared__ uint32_t s_hist[256];
  __shared__ int s_last;
  uint32_t* ctrl  = (uint32_t*)(ws + OFF_CTRL);
  uint32_t* hist0 = (uint32_t*)(ws + OFF_HIST0);
  uint64_t* keys  = (uint64_t*)(ws + OFF_KEYS);
  int32_t*  labs  = (int32_t*)(ws + OFF_LABELS);
  const int tid = threadIdx.x;
  s_hist[tid] = 0;

  // coalesced float4 staging of a 128-prior tile (block range is 16B aligned)
  const float4* src = (const float4*)(scores + (size_t)blockIdx.x * (TILE * NCLS));
  float4* dst = (float4*)s_tile;
  constexpr int NV = TILE * NCLS / 4;  // 2592
  #pragma unroll
  for (int it = 0; it < (NV + 255) / 256; ++it) {
    int idx = it * 256 + tid;
    if (idx < NV) dst[idx] = src[idx];
  }
  __syncthreads();

  // 2 threads per prior: half 0 -> classes 1..40 (labels 0..39), half 1 -> 41..80
  const int pl = tid >> 1, half = tid & 1;
  const float* row = s_tile + pl * NCLS + 1 + half * 40;
  float best = -1.0f; int lab = 0;
  #pragma unroll
  for (int c = 0; c < 40; ++c) {           // strict > keeps first occurrence
    float v = row[c];
    if (v > best) { best = v; lab = c; }
  }
  lab += half * 40;
  float obst = __shfl_xor(best, 1);
  int   olab = __shfl_xor(lab, 1);
  float b0 = half ? obst : best;  int l0 = half ? olab : lab;
  float b1 = half ? best : obst;  int l1 = half ? lab  : olab;
  float fb = (b1 > b0) ? b1 : b0;          // tie -> half 0 (lower label) = first occurrence
  int   fl = (b1 > b0) ? l1 : l0;

  if (half == 0) {
    int p = blockIdx.x * TILE + pl;
    uint32_t bits = __float_as_uint(fb);   // scores >= 0: bit order == float order
    keys[p] = ((uint64_t)bits << 32) | (uint32_t)(~(uint32_t)p);
    labs[p] = fl;
    atomicAdd(&s_hist[bits >> 24], 1u);
  }
  __syncthreads();
  uint32_t h = s_hist[tid];
  if (h) atomicAdd(&hist0[tid], h);
  __threadfence();
  __syncthreads();
  if (tid == 0) s_last = (atomicAdd(&ctrl[3], 1u) == (uint32_t)(gridDim.x - 1));
  __syncthreads();
  if (s_last && tid == 0) {
    __threadfence();
    select_digit(hist0, TOPK, 0u, 24, ctrl);   // radix pass 0 select
  }
}

// ---- Phase 2/3: radix passes on score bytes 2 and 1, with fused select ----
template <int P>
__global__ __launch_bounds__(256) void k_hist(uint8_t* __restrict__ ws) {
  __shared__ uint32_t s_hist[256];
  __shared__ int s_last;
  uint32_t* ctrl = (uint32_t*)(ws + OFF_CTRL);
  uint32_t* hist = (uint32_t*)(ws + (P == 1 ? OFF_HIST1 : OFF_HIST2));
  const uint64_t* keys = (const uint64_t*)(ws + OFF_KEYS);
  const int tid = threadIdx.x;
  s_hist[tid] = 0;
  __syncthreads();
  const uint32_t prefix = ctrl[0];
  constexpr int SH_MATCH = 32 - 8 * P;
  constexpr int SH_DIG   = 24 - 8 * P;
  const uint32_t pm = prefix >> SH_MATCH;
  for (int i = blockIdx.x * 256 + tid; i < N_PRIORS; i += 256 * HGRID) {
    uint32_t bits = (uint32_t)(keys[i] >> 32);
    if ((bits >> SH_MATCH) == pm) atomicAdd(&s_hist[(bits >> SH_DIG) & 255u], 1u);
  }
  __syncthreads();
  uint32_t h = s_hist[tid];
  if (h) atomicAdd(&hist[tid], h);
  __threadfence();
  __syncthreads();
  if (tid == 0) s_last = (atomicAdd(&ctrl[3 + P], 1u) == (uint32_t)(gridDim.x - 1));
  __syncthreads();
  if (s_last && tid == 0) {
    __threadfence();
    select_digit(hist, ctrl[1], prefix, SH_DIG, ctrl);
  }
}

// ---- Phase 4: compact candidate superset (score top-24 bits >= threshold prefix) ----
__global__ __launch_bounds__(256) void k_compact(uint8_t* __restrict__ ws) {
  uint32_t* ctrl = (uint32_t*)(ws + OFF_CTRL);
  const uint64_t* keys = (const uint64_t*)(ws + OFF_KEYS);
  uint64_t* cand = (uint64_t*)(ws + OFF_CAND);
  const uint32_t thr = ctrl[0];   // low byte is 0 => bits >= thr <=> top24 >= thr>>8
  const int tid = threadIdx.x;
  for (int i = blockIdx.x * 256 + tid; i < N_PRIORS; i += 256 * HGRID) {
    uint64_t kk = keys[i];
    if ((uint32_t)(kk >> 32) >= thr) {
      uint32_t pos = atomicAdd(&ctrl[2], 1u);
      if (pos < CAND_CAP) cand[pos] = kk;
    }
  }
}

// ---- Phase 5: exact rank (pairwise) + scatter top-1000 in top_k order ----
__global__ __launch_bounds__(256) void k_rank(const float* __restrict__ boxes,
                                              uint8_t* __restrict__ ws) {
  uint32_t* ctrl = (uint32_t*)(ws + OFF_CTRL);
  const uint64_t* cand = (const uint64_t*)(ws + OFF_CAND);
  const int32_t* labs = (const int32_t*)(ws + OFF_LABELS);
  float*   cscore = (float*)(ws + OFF_CSCORE);
  int32_t* clabel = (int32_t*)(ws + OFF_CLABEL);
  float*   craw   = (float*)(ws + OFF_CRAW);
  float*   obox   = (float*)(ws + OFF_OBOX);
  float*   oarea  = (float*)(ws + OFF_OAREA);
  uint64_t* validm = (uint64_t*)(ws + OFF_VALID);
  uint32_t c2 = ctrl[2];
  const uint32_t n = (c2 < CAND_CAP) ? c2 : CAND_CAP;
  const uint32_t j = blockIdx.x;
  if (j >= n) return;
  const uint64_t kj = cand[j];
  const int tid = threadIdx.x;
  uint32_t cnt = 0;
  for (uint32_t i = tid; i < n; i += 256) cnt += (cand[i] > kj) ? 1u : 0u;
  __shared__ uint32_t red[256];
  red[tid] = cnt;
  __syncthreads();
  #pragma unroll
  for (int s = 128; s > 0; s >>= 1) {
    if (tid < s) red[tid] += red[tid + s];
    __syncthreads();
  }
  if (tid == 0) {
    uint32_t rank = red[0];   // keys unique -> ranks unique & complete for top-1000
    if (rank < TOPK) {
      uint32_t idx = ~(uint32_t)kj;
      float sc = __uint_as_float((uint32_t)(kj >> 32));
      int lab = labs[idx];
      float bx0 = boxes[idx * 4 + 0];
      float bx1 = boxes[idx * 4 + 1];
      float bx2 = boxes[idx * 4 + 2];
      float bx3 = boxes[idx * 4 + 3];
      float off = (float)lab * 4.0f;
      float o0 = bx0 + off, o1 = bx1 + off, o2 = bx2 + off, o3 = bx3 + off;
      cscore[rank] = sc;
      clabel[rank] = lab;
      craw[rank * 4 + 0] = bx0; craw[rank * 4 + 1] = bx1;
      craw[rank * 4 + 2] = bx2; craw[rank * 4 + 3] = bx3;
      obox[rank * 4 + 0] = o0;  obox[rank * 4 + 1] = o1;
      obox[rank * 4 + 2] = o2;  obox[rank * 4 + 3] = o3;
      oarea[rank] = (o2 - o0) * (o3 - o1);   // area of offset box, like reference
      if (sc > 0.3f)
        atomicOr((unsigned long long*)&validm[rank >> 6], 1ull << (rank & 63));
    }
  }
}

// ---- Phase 6: IoU bit-matrix + (last block) serial NMS + output ----
__global__ __launch_bounds__(256) void k_iou_nms(float* __restrict__ out,
                                                 uint8_t* __restrict__ ws) {
  __shared__ uint64_t s_any[4];
  __shared__ int s_last;
  __shared__ uint64_t s_keep[16];
  uint32_t* ctrl = (uint32_t*)(ws + OFF_CTRL);
  const float* obox  = (const float*)(ws + OFF_OBOX);
  const float* oarea = (const float*)(ws + OFF_OAREA);
  uint64_t* M   = (uint64_t*)(ws + OFF_M);
  uint64_t* rnz = (uint64_t*)(ws + OFF_RNZ);
  const uint64_t* validm = (const uint64_t*)(ws + OFF_VALID);
  const float*   cscore = (const float*)(ws + OFF_CSCORE);
  const int32_t* clabel = (const int32_t*)(ws + OFF_CLABEL);
  const float*   craw   = (const float*)(ws + OFF_CRAW);

  const int i = blockIdx.x;
  const int tid = threadIdx.x;
  const float bi0 = obox[i * 4 + 0], bi1 = obox[i * 4 + 1];
  const float bi2 = obox[i * 4 + 2], bi3 = obox[i * 4 + 3];
  const float ai = oarea[i];
  uint64_t any = 0;
  #pragma unroll
  for (int k = 0; k < 4; ++k) {
    int j = tid + 256 * k;                      // j in [0,1024); >=1000 slots zeroed
    const float4 bj = ((const float4*)obox)[j];
    float x1 = fmaxf(bi0, bj.x);
    float y1 = fmaxf(bi1, bj.y);
    float x2 = fminf(bi2, bj.z);
    float y2 = fminf(bi3, bj.w);
    float iw = fmaxf(x2 - x1, 0.0f);
    float ih = fmaxf(y2 - y1, 0.0f);
    float inter = iw * ih;
    float uni = ai + oarea[j] - inter;
    float iou = inter / fmaxf(uni, 1e-9f);
    bool pred = (iou > 0.5f) && (j > i) && (j < TOPK);
    uint64_t m = __ballot(pred);
    if ((tid & 63) == 0) atomStoreU64(&M[(size_t)i * 16 + (tid >> 6) + 4 * k], m);
    any |= m;
  }
  if ((tid & 63) == 0) s_any[tid >> 6] = any;
  __syncthreads();
  if (tid == 0) {
    uint64_t a = s_any[0] | s_any[1] | s_any[2] | s_any[3];
    if (a) atomicOr((unsigned long long*)&rnz[i >> 6], 1ull << (i & 63));
  }
  __threadfence();
  __syncthreads();
  if (tid == 0) s_last = (atomicAdd(&ctrl[6], 1u) == (uint32_t)(gridDim.x - 1));
  __syncthreads();
  if (!s_last) return;
  __threadfence();

  // serial NMS on wave 0; lane l<16 owns keep word l; ctz-skip over kept&rownz
  if (tid < 64) {
    const int lane = tid;
    uint64_t keep = 0, rz = 0;
    if (lane < 16) {
      keep = validm[lane];            // written by previous kernel
      rz = atomLoadU64(&rnz[lane]);   // written this kernel -> coherent load
    }
    for (int w = 0; w < 16; ++w) {
      uint64_t rw = __shfl(rz, w);
      int start = 0;
      while (true) {
        uint64_t kw = __shfl(keep, w);
        uint64_t act = kw & rw;
        if (start) act &= (~0ull) << start;
        if (!act) break;
        int il = __builtin_ctzll(act);
        uint64_t m = 0;
        if (lane < 16) m = atomLoadU64(&M[(size_t)(w * 64 + il) * 16 + lane]);
        keep &= ~m;
        if (il >= 63) break;
        start = il + 1;
      }
    }
    if (lane < 16) s_keep[lane] = keep;
  }
  __syncthreads();

  // outputs: boxes[4000] | labels[1000] | probs[1000] | keep[1000], all f32
  for (int e = tid; e < 4000; e += 256) {
    int j = e >> 2;
    bool kp = (s_keep[j >> 6] >> (j & 63)) & 1ull;
    out[e] = kp ? craw[e] : 0.0f;
  }
  for (int j = tid; j < TOPK; j += 256) {
    bool kp = (s_keep[j >> 6] >> (j & 63)) & 1ull;
    out[4000 + j] = kp ? (float)(clabel[j] + 1) : 0.0f;
    out[5000 + j] = kp ? cscore[j] : 0.0f;
    out[6000 + j] = kp ? 1.0f : 0.0f;
  }
}

extern "C" void kernel_launch(void* const* d_in, const int* in_sizes, int n_in,
                              void* d_out, int out_size, void* d_ws, size_t ws_size,
                              hipStream_t stream) {
  const float* scores = (const float*)d_in[0];
  const float* boxes  = (const float*)d_in[1];
  float* out = (float*)d_out;
  uint8_t* ws = (uint8_t*)d_ws;

  (void)in_sizes; (void)n_in; (void)out_size; (void)ws_size;

  hipMemsetAsync(d_ws, 0, 65536, stream);
  k_reduce<<<RED_BLOCKS, 256, 0, stream>>>(scores, ws);
  k_hist<1><<<HGRID, 256, 0, stream>>>(ws);
  k_hist<2><<<HGRID, 256, 0, stream>>>(ws);
  k_compact<<<HGRID, 256, 0, stream>>>(ws);
  k_rank<<<CAND_CAP, 256, 0, stream>>>(boxes, ws);
  k_iou_nms<<<TOPK, 256, 0, stream>>>(out, ws);
}

// Round 2
// 279.959 us; speedup vs baseline: 2.1717x; 2.1717x over previous
//
#include <hip/hip_runtime.h>
#include <stdint.h>

#pragma clang fp contract(off)

#define N_PRIORS   400000
#define NCLS       81
#define TILE       128
#define RED_BLOCKS (N_PRIORS / TILE)   // 3125
#define HGRID      512
#define CAND_CAP   8192
#define TOPK       1000
#define CM_CAP     448                 // rows cached in LDS for serial NMS

// ---- workspace layout (bytes). First 65536 bytes zeroed each launch. ----
// ctrl[16]: [0]=prefix/threshold [1]=krem [2]=cand_cnt [3]=master done (reduce)
//           [4]=done hist1 [5]=done hist2 [6]=done iou [7]=CM slot counter
//           [8..15]=sub done counters (reduce, blockIdx&7)
#define OFF_CTRL    0
#define OFF_HIST0   64       // u32[256]
#define OFF_HIST1   1088
#define OFF_HIST2   2112
#define OFF_RNZ     3200     // u64[16] row-has-suppression bits
#define OFF_VALID   3328     // u64[16] valid bits (score > 0.3)
#define OFF_SLOT    4096     // u32[1000] row -> CM slot+1 (0 = none)
#define OFF_CSCORE  8192     // f32[1024]
#define OFF_CLABEL  12288    // s32[1024]
#define OFF_CRAW    16384    // f32[1024][4] raw boxes
#define OFF_OBOX    32768    // f32[1024][4] offset boxes (zeroed tail)
#define OFF_OAREA   49152    // f32[1024]
#define OFF_CAND    65536    // u64[8192]
#define OFF_CM      131072   // u64[1000][16] compacted suppression rows
#define OFF_KEYS    262144   // u64[400000]
#define OFF_LABELS  (OFF_KEYS + N_PRIORS * 8)  // s32[400000]

__device__ __forceinline__ uint32_t atomLoadU32(const uint32_t* p) {
  return __hip_atomic_load(p, __ATOMIC_RELAXED, __HIP_MEMORY_SCOPE_AGENT);
}
__device__ __forceinline__ uint64_t atomLoadU64(const uint64_t* p) {
  return __hip_atomic_load(p, __ATOMIC_RELAXED, __HIP_MEMORY_SCOPE_AGENT);
}
__device__ __forceinline__ void atomStoreU64(uint64_t* p, uint64_t v) {
  __hip_atomic_store(p, v, __ATOMIC_RELAXED, __HIP_MEMORY_SCOPE_AGENT);
}
__device__ __forceinline__ void atomStoreU32(uint32_t* p, uint32_t v) {
  __hip_atomic_store(p, v, __ATOMIC_RELAXED, __HIP_MEMORY_SCOPE_AGENT);
}

// Wave-parallel digit select: find digit d (descending) with cum(>d) < k <= cum(>=d).
// 64 lanes x 4 bins, parallel loads + shfl_up scan. Call with tid<64.
__device__ __forceinline__ void select_digit_wave(const uint32_t* hist, uint32_t k,
                                                  uint32_t prefix, int sh_dig,
                                                  uint32_t* ctrl, int lane) {
  uint32_t h[4];
  #pragma unroll
  for (int t = 0; t < 4; ++t) h[t] = atomLoadU32(&hist[255 - (4 * lane + t)]);
  uint32_t part = h[0] + h[1] + h[2] + h[3];
  uint32_t incl = part;
  #pragma unroll
  for (int d = 1; d < 64; d <<= 1) {
    uint32_t up = __shfl_up(incl, d);
    if (lane >= d) incl += up;
  }
  uint32_t excl = incl - part;
  if (excl < k && k <= incl) {          // exactly one lane
    uint32_t cum = excl;
    #pragma unroll
    for (int t = 0; t < 4; ++t) {
      if (cum + h[t] >= k) {
        ctrl[0] = prefix | ((uint32_t)(255 - (4 * lane + t)) << sh_dig);
        ctrl[1] = k - cum;
        break;
      }
      cum += h[t];
    }
  }
}

// ---- Phase 1: per-prior max/argmax over classes 1..80 + key pack + hist pass 0 ----
__global__ __launch_bounds__(256) void k_reduce(const float* __restrict__ scores,
                                                uint8_t* __restrict__ ws) {
  __shared__ float s_tile[TILE * NCLS];     // 41472 B
  __shared__ uint32_t s_hist[256];
  __shared__ int s_last;
  uint32_t* ctrl  = (uint32_t*)(ws + OFF_CTRL);
  uint32_t* hist0 = (uint32_t*)(ws + OFF_HIST0);
  uint64_t* keys  = (uint64_t*)(ws + OFF_KEYS);
  int32_t*  labs  = (int32_t*)(ws + OFF_LABELS);
  const int tid = threadIdx.x;
  s_hist[tid] = 0;

  // coalesced float4 staging of a 128-prior tile
  const float4* src = (const float4*)(scores + (size_t)blockIdx.x * (TILE * NCLS));
  float4* dst = (float4*)s_tile;
  constexpr int NV = TILE * NCLS / 4;  // 2592
  #pragma unroll
  for (int it = 0; it < (NV + 255) / 256; ++it) {
    int idx = it * 256 + tid;
    if (idx < NV) dst[idx] = src[idx];
  }
  __syncthreads();

  // 2 threads per prior: half 0 -> classes 1..40 (labels 0..39), half 1 -> 41..80
  const int pl = tid >> 1, half = tid & 1;
  const float* row = s_tile + pl * NCLS + 1 + half * 40;
  float best = -1.0f; int lab = 0;
  #pragma unroll
  for (int c = 0; c < 40; ++c) {           // strict > keeps first occurrence
    float v = row[c];
    if (v > best) { best = v; lab = c; }
  }
  lab += half * 40;
  float obst = __shfl_xor(best, 1);
  int   olab = __shfl_xor(lab, 1);
  float b0 = half ? obst : best;  int l0 = half ? olab : lab;
  float b1 = half ? best : obst;  int l1 = half ? lab  : olab;
  float fb = (b1 > b0) ? b1 : b0;          // tie -> lower label = first occurrence
  int   fl = (b1 > b0) ? l1 : l0;

  if (half == 0) {
    int p = blockIdx.x * TILE + pl;
    uint32_t bits = __float_as_uint(fb);   // scores >= 0: bit order == float order
    keys[p] = ((uint64_t)bits << 32) | (uint32_t)(~(uint32_t)p);
    labs[p] = fl;
    atomicAdd(&s_hist[bits >> 24], 1u);
  }
  __syncthreads();
  uint32_t h = s_hist[tid];
  if (h) atomicAdd(&hist0[tid], h);        // fire-and-forget, LDS-aggregated
  __syncthreads();                         // drains vmcnt(0) before barrier release
  if (tid == 0) {
    // two-level done counter: 8 sub-counters cut same-address RMW contention 8x
    int r = blockIdx.x & 7;
    uint32_t target = (RED_BLOCKS >> 3) + ((uint32_t)r < (RED_BLOCKS & 7) ? 1u : 0u);
    int last = 0;
    if (atomicAdd(&ctrl[8 + r], 1u) == target - 1u)
      last = (atomicAdd(&ctrl[3], 1u) == 7u);
    s_last = last;
  }
  __syncthreads();
  if (s_last && tid < 64)
    select_digit_wave(hist0, TOPK, 0u, 24, ctrl, tid);
}

// ---- Phase 2/3: radix passes on score bytes 2 and 1, with fused wave select ----
template <int P>
__global__ __launch_bounds__(256) void k_hist(uint8_t* __restrict__ ws) {
  __shared__ uint32_t s_hist[256];
  __shared__ int s_last;
  uint32_t* ctrl = (uint32_t*)(ws + OFF_CTRL);
  uint32_t* hist = (uint32_t*)(ws + (P == 1 ? OFF_HIST1 : OFF_HIST2));
  const uint64_t* keys = (const uint64_t*)(ws + OFF_KEYS);
  const int tid = threadIdx.x;
  s_hist[tid] = 0;
  __syncthreads();
  const uint32_t prefix = ctrl[0];
  constexpr int SH_MATCH = 32 - 8 * P;
  constexpr int SH_DIG   = 24 - 8 * P;
  const uint32_t pm = prefix >> SH_MATCH;
  for (int i = blockIdx.x * 256 + tid; i < N_PRIORS; i += 256 * HGRID) {
    uint32_t bits = (uint32_t)(keys[i] >> 32);
    if ((bits >> SH_MATCH) == pm) atomicAdd(&s_hist[(bits >> SH_DIG) & 255u], 1u);
  }
  __syncthreads();
  uint32_t h = s_hist[tid];
  if (h) atomicAdd(&hist[tid], h);
  __syncthreads();                          // drain before done-count
  if (tid == 0) s_last = (atomicAdd(&ctrl[3 + P], 1u) == (uint32_t)(HGRID - 1));
  __syncthreads();
  if (s_last && tid < 64)
    select_digit_wave(hist, ctrl[1], prefix, SH_DIG, ctrl, tid);
}

// ---- Phase 4: compact candidate superset (top-24-bit >= threshold prefix) ----
__global__ __launch_bounds__(256) void k_compact(uint8_t* __restrict__ ws) {
  uint32_t* ctrl = (uint32_t*)(ws + OFF_CTRL);
  const uint64_t* keys = (const uint64_t*)(ws + OFF_KEYS);
  uint64_t* cand = (uint64_t*)(ws + OFF_CAND);
  const uint32_t thr = ctrl[0];   // low byte 0 => bits >= thr <=> top24 >= thr>>8
  const int tid = threadIdx.x;
  for (int i = blockIdx.x * 256 + tid; i < N_PRIORS; i += 256 * HGRID) {
    uint64_t kk = keys[i];
    if ((uint32_t)(kk >> 32) >= thr) {
      uint32_t pos = atomicAdd(&ctrl[2], 1u);
      if (pos < CAND_CAP) cand[pos] = kk;
    }
  }
}

// ---- Phase 5: exact rank (pairwise) + scatter top-1000 in top_k order ----
__global__ __launch_bounds__(256) void k_rank(const float* __restrict__ boxes,
                                              uint8_t* __restrict__ ws) {
  uint32_t* ctrl = (uint32_t*)(ws + OFF_CTRL);
  const uint64_t* cand = (const uint64_t*)(ws + OFF_CAND);
  const int32_t* labs = (const int32_t*)(ws + OFF_LABELS);
  float*   cscore = (float*)(ws + OFF_CSCORE);
  int32_t* clabel = (int32_t*)(ws + OFF_CLABEL);
  float*   craw   = (float*)(ws + OFF_CRAW);
  float*   obox   = (float*)(ws + OFF_OBOX);
  float*   oarea  = (float*)(ws + OFF_OAREA);
  uint64_t* validm = (uint64_t*)(ws + OFF_VALID);
  uint32_t c2 = ctrl[2];
  const uint32_t n = (c2 < CAND_CAP) ? c2 : CAND_CAP;
  const uint32_t j = blockIdx.x;
  if (j >= n) return;
  const uint64_t kj = cand[j];
  const int tid = threadIdx.x;
  uint32_t cnt = 0;
  for (uint32_t i = tid; i < n; i += 256) cnt += (cand[i] > kj) ? 1u : 0u;
  __shared__ uint32_t red[256];
  red[tid] = cnt;
  __syncthreads();
  #pragma unroll
  for (int s = 128; s > 0; s >>= 1) {
    if (tid < s) red[tid] += red[tid + s];
    __syncthreads();
  }
  if (tid == 0) {
    uint32_t rank = red[0];   // keys unique -> ranks unique & complete for top-1000
    if (rank < TOPK) {
      uint32_t idx = ~(uint32_t)kj;
      float sc = __uint_as_float((uint32_t)(kj >> 32));
      int lab = labs[idx];
      float bx0 = boxes[idx * 4 + 0];
      float bx1 = boxes[idx * 4 + 1];
      float bx2 = boxes[idx * 4 + 2];
      float bx3 = boxes[idx * 4 + 3];
      float off = (float)lab * 4.0f;
      float o0 = bx0 + off, o1 = bx1 + off, o2 = bx2 + off, o3 = bx3 + off;
      cscore[rank] = sc;
      clabel[rank] = lab;
      craw[rank * 4 + 0] = bx0; craw[rank * 4 + 1] = bx1;
      craw[rank * 4 + 2] = bx2; craw[rank * 4 + 3] = bx3;
      obox[rank * 4 + 0] = o0;  obox[rank * 4 + 1] = o1;
      obox[rank * 4 + 2] = o2;  obox[rank * 4 + 3] = o3;
      oarea[rank] = (o2 - o0) * (o3 - o1);
      if (sc > 0.3f)
        atomicOr((unsigned long long*)&validm[rank >> 6], 1ull << (rank & 63));
    }
  }
}

// ---- Phase 6: IoU rows (compacted) + (last block) LDS-cached serial NMS + output ----
__global__ __launch_bounds__(256) void k_iou_nms(float* __restrict__ out,
                                                 uint8_t* __restrict__ ws) {
  __shared__ uint64_t s_words[16];
  __shared__ uint32_t s_slotsh;
  __shared__ int s_last;
  __shared__ uint64_t s_keep[16];
  __shared__ uint16_t s_slot[TOPK];          // 2000 B
  __shared__ uint64_t s_cm[CM_CAP * 16];     // 57344 B

  uint32_t* ctrl = (uint32_t*)(ws + OFF_CTRL);
  const float* obox  = (const float*)(ws + OFF_OBOX);
  const float* oarea = (const float*)(ws + OFF_OAREA);
  uint64_t* CM  = (uint64_t*)(ws + OFF_CM);
  uint64_t* rnz = (uint64_t*)(ws + OFF_RNZ);
  uint32_t* slotmap = (uint32_t*)(ws + OFF_SLOT);
  const uint64_t* validm = (const uint64_t*)(ws + OFF_VALID);
  const float*   cscore = (const float*)(ws + OFF_CSCORE);
  const int32_t* clabel = (const int32_t*)(ws + OFF_CLABEL);
  const float*   craw   = (const float*)(ws + OFF_CRAW);

  const int i = blockIdx.x;
  const int tid = threadIdx.x;
  const float bi0 = obox[i * 4 + 0], bi1 = obox[i * 4 + 1];
  const float bi2 = obox[i * 4 + 2], bi3 = obox[i * 4 + 3];
  const float ai = oarea[i];
  #pragma unroll
  for (int k = 0; k < 4; ++k) {
    int j = tid + 256 * k;                      // [0,1024); >=1000 masked below
    const float4 bj = ((const float4*)obox)[j];
    float x1 = fmaxf(bi0, bj.x);
    float y1 = fmaxf(bi1, bj.y);
    float x2 = fminf(bi2, bj.z);
    float y2 = fminf(bi3, bj.w);
    float iw = fmaxf(x2 - x1, 0.0f);
    float ih = fmaxf(y2 - y1, 0.0f);
    float inter = iw * ih;
    float uni = ai + oarea[j] - inter;
    float iou = inter / fmaxf(uni, 1e-9f);
    bool pred = (iou > 0.5f) && (j > i) && (j < TOPK);
    uint64_t m = __ballot(pred);
    if ((tid & 63) == 0) s_words[(tid >> 6) + 4 * k] = m;
  }
  __syncthreads();
  if (tid == 0) {
    uint64_t any = 0;
    #pragma unroll
    for (int w = 0; w < 16; ++w) any |= s_words[w];
    uint32_t sl = 0xFFFFFFFFu;
    if (any) {
      sl = atomicAdd(&ctrl[7], 1u);
      atomicOr((unsigned long long*)&rnz[i >> 6], 1ull << (i & 63));
      atomStoreU32(&slotmap[i], sl + 1u);
    }
    s_slotsh = sl;
  }
  __syncthreads();
  {
    uint32_t sl = s_slotsh;
    if (sl != 0xFFFFFFFFu && tid < 16)
      atomStoreU64(&CM[(size_t)sl * 16 + tid], s_words[tid]);
  }
  __syncthreads();                            // drain before done-count
  if (tid == 0) s_last = (atomicAdd(&ctrl[6], 1u) == (uint32_t)(TOPK - 1));
  __syncthreads();
  if (!s_last) return;

  // ---- last block: prefetch compacted rows to LDS, serial NMS, outputs ----
  uint32_t cmcnt = atomLoadU32(&ctrl[7]);     // <= 1000
  uint32_t ncm = cmcnt < CM_CAP ? cmcnt : CM_CAP;
  for (int r = tid; r < TOPK; r += 256)
    s_slot[r] = (uint16_t)atomLoadU32(&slotmap[r]);
  for (uint32_t x = tid; x < ncm * 16; x += 256)
    s_cm[x] = atomLoadU64(&CM[x]);
  __syncthreads();

  if (tid < 64) {
    const int lane = tid;
    uint64_t keep = 0, rz = 0;
    if (lane < 16) {
      keep = validm[lane];            // written by previous kernel (boundary-coherent)
      rz = atomLoadU64(&rnz[lane]);
    }
    for (int w = 0; w < 16; ++w) {
      uint64_t rw = __shfl(rz, w);
      int start = 0;
      while (true) {
        uint64_t kw = __shfl(keep, w);
        uint64_t act = kw & rw;
        if (start) act &= (~0ull) << start;
        if (!act) break;
        int il = __builtin_ctzll(act);
        int row = w * 64 + il;
        uint32_t sv = s_slot[row];
        uint64_t m = 0;
        if (lane < 16 && sv) {
          uint32_t s = sv - 1u;
          m = (s < ncm) ? s_cm[s * 16 + lane]
                        : atomLoadU64(&CM[(size_t)s * 16 + lane]);
        }
        keep &= ~m;
        if (il >= 63) break;
        start = il + 1;
      }
    }
    if (lane < 16) s_keep[lane] = keep;
  }
  __syncthreads();

  // outputs: boxes[4000] | labels[1000] | probs[1000] | keep[1000], all f32
  for (int e = tid; e < 4000; e += 256) {
    int j = e >> 2;
    bool kp = (s_keep[j >> 6] >> (j & 63)) & 1ull;
    out[e] = kp ? craw[e] : 0.0f;
  }
  for (int j = tid; j < TOPK; j += 256) {
    bool kp = (s_keep[j >> 6] >> (j & 63)) & 1ull;
    out[4000 + j] = kp ? (float)(clabel[j] + 1) : 0.0f;
    out[5000 + j] = kp ? cscore[j] : 0.0f;
    out[6000 + j] = kp ? 1.0f : 0.0f;
  }
}

extern "C" void kernel_launch(void* const* d_in, const int* in_sizes, int n_in,
                              void* d_out, int out_size, void* d_ws, size_t ws_size,
                              hipStream_t stream) {
  const float* scores = (const float*)d_in[0];
  const float* boxes  = (const float*)d_in[1];
  float* out = (float*)d_out;
  uint8_t* ws = (uint8_t*)d_ws;

  (void)in_sizes; (void)n_in; (void)out_size; (void)ws_size;

  hipMemsetAsync(d_ws, 0, 65536, stream);
  k_reduce<<<RED_BLOCKS, 256, 0, stream>>>(scores, ws);
  k_hist<1><<<HGRID, 256, 0, stream>>>(ws);
  k_hist<2><<<HGRID, 256, 0, stream>>>(ws);
  k_compact<<<HGRID, 256, 0, stream>>>(ws);
  k_rank<<<CAND_CAP, 256, 0, stream>>>(boxes, ws);
  k_iou_nms<<<TOPK, 256, 0, stream>>>(out, ws);
}

// Round 4
// 265.644 us; speedup vs baseline: 2.2887x; 1.0539x over previous
//
#include <hip/hip_runtime.h>
#include <stdint.h>

#pragma clang fp contract(off)

#define N_PRIORS   400000
#define NCLS       81
#define TILE       128
#define RED_BLOCKS (N_PRIORS / TILE)   // 3125
#define HGRID      512
#define CAND_CAP   8192
#define TOPK       1000
#define CM_CAP     448                 // rows cached in LDS for serial NMS

// ---- workspace layout (bytes). First 65536 bytes zeroed each launch. ----
// ctrl[16]: [0]=prefix/threshold [1]=krem [2]=cand_cnt [3]=master done (reduce)
//           [4]=done hist1 [5]=done hist2 [6]=done iou [7]=CM slot counter
//           [8..15]=sub done counters (reduce, blockIdx&7)
#define OFF_CTRL    0
#define OFF_HIST0   64       // u32[256]
#define OFF_HIST1   1088
#define OFF_HIST2   2112
#define OFF_RNZ     3200     // u64[16] row-has-suppression bits
#define OFF_VALID   3328     // u64[16] valid bits (score > 0.3)
#define OFF_SLOT    4096     // u32[1000] row -> CM slot+1 (0 = none)
#define OFF_CSCORE  8192     // f32[1024]
#define OFF_CLABEL  12288    // s32[1024]
#define OFF_CRAW    16384    // f32[1024][4] raw boxes
#define OFF_OBOX    32768    // f32[1024][4] offset boxes (zeroed tail)
#define OFF_OAREA   49152    // f32[1024]
#define OFF_CAND    65536    // u64[8192]
#define OFF_CM      131072   // u64[1000][16] compacted suppression rows
#define OFF_KEYS    262144   // u64[400000]
#define OFF_LABELS  (OFF_KEYS + N_PRIORS * 8)  // s32[400000]

__device__ __forceinline__ uint32_t atomLoadU32(const uint32_t* p) {
  return __hip_atomic_load(p, __ATOMIC_RELAXED, __HIP_MEMORY_SCOPE_AGENT);
}
__device__ __forceinline__ uint64_t atomLoadU64(const uint64_t* p) {
  return __hip_atomic_load(p, __ATOMIC_RELAXED, __HIP_MEMORY_SCOPE_AGENT);
}
__device__ __forceinline__ void atomStoreU64(uint64_t* p, uint64_t v) {
  __hip_atomic_store(p, v, __ATOMIC_RELAXED, __HIP_MEMORY_SCOPE_AGENT);
}
__device__ __forceinline__ void atomStoreU32(uint32_t* p, uint32_t v) {
  __hip_atomic_store(p, v, __ATOMIC_RELAXED, __HIP_MEMORY_SCOPE_AGENT);
}

// async HBM->LDS DMA, 16B per lane; LDS dest = wave-uniform base + lane*16
__device__ __forceinline__ void gload_lds16(const void* g, void* l) {
  __builtin_amdgcn_global_load_lds(
      (const __attribute__((address_space(1))) void*)g,
      (__attribute__((address_space(3))) void*)l, 16, 0, 0);
}

// Wave-parallel digit select: find digit d (descending) with cum(>d) < k <= cum(>=d).
// 64 lanes x 4 bins, parallel loads + shfl_up scan. Call with tid<64.
__device__ __forceinline__ void select_digit_wave(const uint32_t* hist, uint32_t k,
                                                  uint32_t prefix, int sh_dig,
                                                  uint32_t* ctrl, int lane) {
  uint32_t h[4];
  #pragma unroll
  for (int t = 0; t < 4; ++t) h[t] = atomLoadU32(&hist[255 - (4 * lane + t)]);
  uint32_t part = h[0] + h[1] + h[2] + h[3];
  uint32_t incl = part;
  #pragma unroll
  for (int d = 1; d < 64; d <<= 1) {
    uint32_t up = __shfl_up(incl, d);
    if (lane >= d) incl += up;
  }
  uint32_t excl = incl - part;
  if (excl < k && k <= incl) {          // exactly one lane
    uint32_t cum = excl;
    #pragma unroll
    for (int t = 0; t < 4; ++t) {
      if (cum + h[t] >= k) {
        ctrl[0] = prefix | ((uint32_t)(255 - (4 * lane + t)) << sh_dig);
        ctrl[1] = k - cum;
        break;
      }
      cum += h[t];
    }
  }
}

// ---- Phase 1: per-prior max/argmax over classes 1..80 + key pack + hist pass 0 ----
__global__ __launch_bounds__(256) void k_reduce(const float* __restrict__ scores,
                                                uint8_t* __restrict__ ws) {
  __shared__ __align__(16) float s_tile[TILE * NCLS];  // 41472 B
  __shared__ uint32_t s_hist[256];
  __shared__ int s_last;
  uint32_t* ctrl  = (uint32_t*)(ws + OFF_CTRL);
  uint32_t* hist0 = (uint32_t*)(ws + OFF_HIST0);
  uint64_t* keys  = (uint64_t*)(ws + OFF_KEYS);
  int32_t*  labs  = (int32_t*)(ws + OFF_LABELS);
  const int tid = threadIdx.x;
  s_hist[tid] = 0;

  // HBM->LDS DMA staging of the 128-prior tile: 40 x 1KB chunks round-robin
  // across the 4 waves (no register round-trip -> full chunk in flight).
  const float* src = scores + (size_t)blockIdx.x * (TILE * NCLS);
  {
    const int wave = tid >> 6, lane = tid & 63;
    const char* gbase = (const char*)src + lane * 16;
    char* lbase = (char*)s_tile;
    #pragma unroll
    for (int c = wave; c < 40; c += 4)
      gload_lds16(gbase + c * 1024, lbase + c * 1024);
  }
  // tail 512B (floats [10240,10368)): half-wave reg-staged
  if (tid < 32) {
    float4 v = ((const float4*)src)[2560 + tid];
    ((float4*)s_tile)[2560 + tid] = v;
  }
  __syncthreads();   // drains vmcnt (DMA) + lgkmcnt (tail ds_write)

  // 2 threads per prior: half 0 -> classes 1..40 (labels 0..39), half 1 -> 41..80
  const int pl = tid >> 1, half = tid & 1;
  const float* row = s_tile + pl * NCLS + 1 + half * 40;
  float best = -1.0f; int lab = 0;
  #pragma unroll
  for (int c = 0; c < 40; ++c) {           // strict > keeps first occurrence
    float v = row[c];
    if (v > best) { best = v; lab = c; }
  }
  lab += half * 40;
  float obst = __shfl_xor(best, 1);
  int   olab = __shfl_xor(lab, 1);
  float b0 = half ? obst : best;  int l0 = half ? olab : lab;
  float b1 = half ? best : obst;  int l1 = half ? lab  : olab;
  float fb = (b1 > b0) ? b1 : b0;          // tie -> lower label = first occurrence
  int   fl = (b1 > b0) ? l1 : l0;

  if (half == 0) {
    int p = blockIdx.x * TILE + pl;
    uint32_t bits = __float_as_uint(fb);   // scores >= 0: bit order == float order
    keys[p] = ((uint64_t)bits << 32) | (uint32_t)(~(uint32_t)p);
    labs[p] = fl;
    atomicAdd(&s_hist[bits >> 24], 1u);
  }
  __syncthreads();
  uint32_t h = s_hist[tid];
  if (h) atomicAdd(&hist0[tid], h);        // fire-and-forget, LDS-aggregated
  __syncthreads();                         // drains vmcnt(0) before barrier release
  if (tid == 0) {
    // two-level done counter: 8 sub-counters cut same-address RMW contention 8x
    int r = blockIdx.x & 7;
    uint32_t target = (RED_BLOCKS >> 3) + ((uint32_t)r < (RED_BLOCKS & 7) ? 1u : 0u);
    int last = 0;
    if (atomicAdd(&ctrl[8 + r], 1u) == target - 1u)
      last = (atomicAdd(&ctrl[3], 1u) == 7u);
    s_last = last;
  }
  __syncthreads();
  if (s_last && tid < 64)
    select_digit_wave(hist0, TOPK, 0u, 24, ctrl, tid);
}

// ---- Phase 2/3: radix passes on score bytes 2 and 1, with fused wave select ----
template <int P>
__global__ __launch_bounds__(256) void k_hist(uint8_t* __restrict__ ws) {
  __shared__ uint32_t s_hist[256];
  __shared__ int s_last;
  uint32_t* ctrl = (uint32_t*)(ws + OFF_CTRL);
  uint32_t* hist = (uint32_t*)(ws + (P == 1 ? OFF_HIST1 : OFF_HIST2));
  const uint64_t* keys = (const uint64_t*)(ws + OFF_KEYS);
  const int tid = threadIdx.x;
  s_hist[tid] = 0;
  __syncthreads();
  const uint32_t prefix = ctrl[0];
  constexpr int SH_MATCH = 32 - 8 * P;
  constexpr int SH_DIG   = 24 - 8 * P;
  const uint32_t pm = prefix >> SH_MATCH;
  for (int i = blockIdx.x * 256 + tid; i < N_PRIORS; i += 256 * HGRID) {
    uint32_t bits = (uint32_t)(keys[i] >> 32);
    if ((bits >> SH_MATCH) == pm) atomicAdd(&s_hist[(bits >> SH_DIG) & 255u], 1u);
  }
  __syncthreads();
  uint32_t h = s_hist[tid];
  if (h) atomicAdd(&hist[tid], h);
  __syncthreads();                          // drain before done-count
  if (tid == 0) s_last = (atomicAdd(&ctrl[3 + P], 1u) == (uint32_t)(HGRID - 1));
  __syncthreads();
  if (s_last && tid < 64)
    select_digit_wave(hist, ctrl[1], prefix, SH_DIG, ctrl, tid);
}

// ---- Phase 4: compact candidate superset (top-24-bit >= threshold prefix) ----
__global__ __launch_bounds__(256) void k_compact(uint8_t* __restrict__ ws) {
  uint32_t* ctrl = (uint32_t*)(ws + OFF_CTRL);
  const uint64_t* keys = (const uint64_t*)(ws + OFF_KEYS);
  uint64_t* cand = (uint64_t*)(ws + OFF_CAND);
  const uint32_t thr = ctrl[0];   // low byte 0 => bits >= thr <=> top24 >= thr>>8
  const int tid = threadIdx.x;
  for (int i = blockIdx.x * 256 + tid; i < N_PRIORS; i += 256 * HGRID) {
    uint64_t kk = keys[i];
    if ((uint32_t)(kk >> 32) >= thr) {
      uint32_t pos = atomicAdd(&ctrl[2], 1u);
      if (pos < CAND_CAP) cand[pos] = kk;
    }
  }
}

// ---- Phase 5: exact rank (pairwise) + scatter top-1000 in top_k order ----
__global__ __launch_bounds__(256) void k_rank(const float* __restrict__ boxes,
                                              uint8_t* __restrict__ ws) {
  uint32_t* ctrl = (uint32_t*)(ws + OFF_CTRL);
  const uint64_t* cand = (const uint64_t*)(ws + OFF_CAND);
  const int32_t* labs = (const int32_t*)(ws + OFF_LABELS);
  float*   cscore = (float*)(ws + OFF_CSCORE);
  int32_t* clabel = (int32_t*)(ws + OFF_CLABEL);
  float*   craw   = (float*)(ws + OFF_CRAW);
  float*   obox   = (float*)(ws + OFF_OBOX);
  float*   oarea  = (float*)(ws + OFF_OAREA);
  uint64_t* validm = (uint64_t*)(ws + OFF_VALID);
  uint32_t c2 = ctrl[2];
  const uint32_t n = (c2 < CAND_CAP) ? c2 : CAND_CAP;
  const uint32_t j = blockIdx.x;
  if (j >= n) return;
  const uint64_t kj = cand[j];
  const int tid = threadIdx.x;
  uint32_t cnt = 0;
  for (uint32_t i = tid; i < n; i += 256) cnt += (cand[i] > kj) ? 1u : 0u;
  __shared__ uint32_t red[256];
  red[tid] = cnt;
  __syncthreads();
  #pragma unroll
  for (int s = 128; s > 0; s >>= 1) {
    if (tid < s) red[tid] += red[tid + s];
    __syncthreads();
  }
  if (tid == 0) {
    uint32_t rank = red[0];   // keys unique -> ranks unique & complete for top-1000
    if (rank < TOPK) {
      uint32_t idx = ~(uint32_t)kj;
      float sc = __uint_as_float((uint32_t)(kj >> 32));
      int lab = labs[idx];
      float bx0 = boxes[idx * 4 + 0];
      float bx1 = boxes[idx * 4 + 1];
      float bx2 = boxes[idx * 4 + 2];
      float bx3 = boxes[idx * 4 + 3];
      float off = (float)lab * 4.0f;
      float o0 = bx0 + off, o1 = bx1 + off, o2 = bx2 + off, o3 = bx3 + off;
      cscore[rank] = sc;
      clabel[rank] = lab;
      craw[rank * 4 + 0] = bx0; craw[rank * 4 + 1] = bx1;
      craw[rank * 4 + 2] = bx2; craw[rank * 4 + 3] = bx3;
      obox[rank * 4 + 0] = o0;  obox[rank * 4 + 1] = o1;
      obox[rank * 4 + 2] = o2;  obox[rank * 4 + 3] = o3;
      oarea[rank] = (o2 - o0) * (o3 - o1);
      if (sc > 0.3f)
        atomicOr((unsigned long long*)&validm[rank >> 6], 1ull << (rank & 63));
    }
  }
}

// ---- Phase 6: IoU rows (compacted) + (last block) LDS-cached serial NMS + output ----
__global__ __launch_bounds__(256) void k_iou_nms(float* __restrict__ out,
                                                 uint8_t* __restrict__ ws) {
  __shared__ uint64_t s_words[16];
  __shared__ uint32_t s_slotsh;
  __shared__ int s_last;
  __shared__ uint64_t s_keep[16];
  __shared__ uint16_t s_slot[TOPK];          // 2000 B
  __shared__ uint64_t s_cm[CM_CAP * 16];     // 57344 B

  uint32_t* ctrl = (uint32_t*)(ws + OFF_CTRL);
  const float* obox  = (const float*)(ws + OFF_OBOX);
  const float* oarea = (const float*)(ws + OFF_OAREA);
  uint64_t* CM  = (uint64_t*)(ws + OFF_CM);
  uint64_t* rnz = (uint64_t*)(ws + OFF_RNZ);
  uint32_t* slotmap = (uint32_t*)(ws + OFF_SLOT);
  const uint64_t* validm = (const uint64_t*)(ws + OFF_VALID);
  const float*   cscore = (const float*)(ws + OFF_CSCORE);
  const int32_t* clabel = (const int32_t*)(ws + OFF_CLABEL);
  const float*   craw   = (const float*)(ws + OFF_CRAW);

  const int i = blockIdx.x;
  const int tid = threadIdx.x;
  const float bi0 = obox[i * 4 + 0], bi1 = obox[i * 4 + 1];
  const float bi2 = obox[i * 4 + 2], bi3 = obox[i * 4 + 3];
  const float ai = oarea[i];
  #pragma unroll
  for (int k = 0; k < 4; ++k) {
    int j = tid + 256 * k;                      // [0,1024); >=1000 masked below
    const float4 bj = ((const float4*)obox)[j];
    float x1 = fmaxf(bi0, bj.x);
    float y1 = fmaxf(bi1, bj.y);
    float x2 = fminf(bi2, bj.z);
    float y2 = fminf(bi3, bj.w);
    float iw = fmaxf(x2 - x1, 0.0f);
    float ih = fmaxf(y2 - y1, 0.0f);
    float inter = iw * ih;
    float uni = ai + oarea[j] - inter;
    float iou = inter / fmaxf(uni, 1e-9f);
    bool pred = (iou > 0.5f) && (j > i) && (j < TOPK);
    uint64_t m = __ballot(pred);
    if ((tid & 63) == 0) s_words[(tid >> 6) + 4 * k] = m;
  }
  __syncthreads();
  if (tid == 0) {
    uint64_t any = 0;
    #pragma unroll
    for (int w = 0; w < 16; ++w) any |= s_words[w];
    uint32_t sl = 0xFFFFFFFFu;
    if (any) {
      sl = atomicAdd(&ctrl[7], 1u);
      atomicOr((unsigned long long*)&rnz[i >> 6], 1ull << (i & 63));
      atomStoreU32(&slotmap[i], sl + 1u);
    }
    s_slotsh = sl;
  }
  __syncthreads();
  {
    uint32_t sl = s_slotsh;
    if (sl != 0xFFFFFFFFu && tid < 16)
      atomStoreU64(&CM[(size_t)sl * 16 + tid], s_words[tid]);
  }
  __syncthreads();                            // drain before done-count
  if (tid == 0) s_last = (atomicAdd(&ctrl[6], 1u) == (uint32_t)(TOPK - 1));
  __syncthreads();
  if (!s_last) return;

  // ---- last block: prefetch compacted rows to LDS, serial NMS, outputs ----
  uint32_t cmcnt = atomLoadU32(&ctrl[7]);     // <= 1000
  uint32_t ncm = cmcnt < CM_CAP ? cmcnt : CM_CAP;
  for (int r = tid; r < TOPK; r += 256)
    s_slot[r] = (uint16_t)atomLoadU32(&slotmap[r]);
  for (uint32_t x = tid; x < ncm * 16; x += 256)
    s_cm[x] = atomLoadU64(&CM[x]);
  __syncthreads();

  if (tid < 64) {
    const int lane = tid;
    uint64_t keep = 0, rz = 0;
    if (lane < 16) {
      keep = validm[lane];            // written by previous kernel (boundary-coherent)
      rz = atomLoadU64(&rnz[lane]);
    }
    for (int w = 0; w < 16; ++w) {
      uint64_t rw = __shfl(rz, w);
      int start = 0;
      while (true) {
        uint64_t kw = __shfl(keep, w);
        uint64_t act = kw & rw;
        if (start) act &= (~0ull) << start;
        if (!act) break;
        int il = __builtin_ctzll(act);
        int row = w * 64 + il;
        uint32_t sv = s_slot[row];
        uint64_t m = 0;
        if (lane < 16 && sv) {
          uint32_t s = sv - 1u;
          m = (s < ncm) ? s_cm[s * 16 + lane]
                        : atomLoadU64(&CM[(size_t)s * 16 + lane]);
        }
        keep &= ~m;
        if (il >= 63) break;
        start = il + 1;
      }
    }
    if (lane < 16) s_keep[lane] = keep;
  }
  __syncthreads();

  // outputs: boxes[4000] | labels[1000] | probs[1000] | keep[1000], all f32
  for (int e = tid; e < 4000; e += 256) {
    int j = e >> 2;
    bool kp = (s_keep[j >> 6] >> (j & 63)) & 1ull;
    out[e] = kp ? craw[e] : 0.0f;
  }
  for (int j = tid; j < TOPK; j += 256) {
    bool kp = (s_keep[j >> 6] >> (j & 63)) & 1ull;
    out[4000 + j] = kp ? (float)(clabel[j] + 1) : 0.0f;
    out[5000 + j] = kp ? cscore[j] : 0.0f;
    out[6000 + j] = kp ? 1.0f : 0.0f;
  }
}

extern "C" void kernel_launch(void* const* d_in, const int* in_sizes, int n_in,
                              void* d_out, int out_size, void* d_ws, size_t ws_size,
                              hipStream_t stream) {
  const float* scores = (const float*)d_in[0];
  const float* boxes  = (const float*)d_in[1];
  float* out = (float*)d_out;
  uint8_t* ws = (uint8_t*)d_ws;

  (void)in_sizes; (void)n_in; (void)out_size; (void)ws_size;

  hipMemsetAsync(d_ws, 0, 65536, stream);
  k_reduce<<<RED_BLOCKS, 256, 0, stream>>>(scores, ws);
  k_hist<1><<<HGRID, 256, 0, stream>>>(ws);
  k_hist<2><<<HGRID, 256, 0, stream>>>(ws);
  k_compact<<<HGRID, 256, 0, stream>>>(ws);
  k_rank<<<CAND_CAP, 256, 0, stream>>>(boxes, ws);
  k_iou_nms<<<TOPK, 256, 0, stream>>>(out, ws);
}